// Round 4
// baseline (501.128 us; speedup 1.0000x reference)
//
#include <hip/hip_runtime.h>
#include <math.h>
#include <stdint.h>

#define NFEA   64
#define NHEAD  3
#define K1_T   256   // threads per MLP block
#define K1_TILE 256  // atoms per staged tile (64 KB)
#define GPB    4     // waves (graphs) per pool block
#define LCAP   256   // atoms per graph cached as float4 e-values (4 KB/wave)

typedef float v2f __attribute__((ext_vector_type(2)));

__device__ __forceinline__ void wave_sync_lds() {
  asm volatile("s_waitcnt lgkmcnt(0)" ::: "memory");
}

// ---------------- segment starts from sorted owner ----------------
__global__ void gar_starts(const int* __restrict__ owner, int* __restrict__ starts,
                           int n_atoms, int n_graphs)
{
  int a = blockIdx.x * blockDim.x + threadIdx.x;
  if (a >= n_atoms) return;
  int cur  = owner[a];
  int prev = (a == 0) ? -1 : owner[a - 1];
  for (int g = prev + 1; g <= cur; ++g) starts[g] = a;
  if (a == n_atoms - 1)
    for (int g = cur + 1; g <= n_graphs; ++g) starts[g] = n_atoms;
}

// ---------------- K1: atom-parallel MLP -> logits4[N] ----------------
// Double-buffered global_load_lds staging (counted vmcnt, raw s_barrier):
// stage tile t+1 while computing tile t. Thread = atom within tile.
__global__ __launch_bounds__(K1_T, 1) void gar_mlp(
    const float* __restrict__ atom_feas,
    const float* __restrict__ W1, const float* __restrict__ b1,
    const float* __restrict__ W2, const float* __restrict__ b2,
    float4* __restrict__ logits4, int n_atoms, int n_tiles)
{
  __shared__ __align__(16) float xs[2][K1_TILE * NFEA];  // 2 x 64 KB
  const int tid = threadIdx.x;
  const int w = tid >> 6, t = tid & 63;
  const char* __restrict__ xbytes = (const char*)atom_feas;

  // Stage tile -> buffer buf. LDS dest is linear (base + lane*16); the XOR
  // swizzle lives on the GLOBAL source address (rule: both-sides-or-neither).
  // LDS[r][s] = x[row(r)][s ^ (r&15)]  (16B slots)
  auto STAGE = [&](int tile, int buf) {
    const unsigned base_row = (unsigned)tile * K1_TILE;
#pragma unroll
    for (int j = 0; j < 16; ++j) {
      const int r = ((j * 4 + w) << 2) + (t >> 4);     // local row 0..255
      unsigned grow = base_row + (unsigned)r;
      if (grow >= (unsigned)n_atoms) grow = (unsigned)n_atoms - 1;  // clamp tail
      const unsigned src = grow * 256u + (unsigned)((((t & 15) ^ (r & 15)) << 4));
      __builtin_amdgcn_global_load_lds(
          (const __attribute__((address_space(1))) void*)(xbytes + src),
          (__attribute__((address_space(3))) void*)
              ((char*)&xs[buf][0] + ((j * 4 + w) << 10) + (t << 4)),
          16, 0, 0);
    }
  };

  int tile = blockIdx.x;
  if (tile >= n_tiles) return;
  STAGE(tile, 0);
  int buf = 0;
  const int key = (tid & 15);

  for (; tile < n_tiles; tile += gridDim.x) {
    const int nxt = tile + gridDim.x;
    if (nxt < n_tiles) {
      STAGE(nxt, buf ^ 1);
      asm volatile("s_waitcnt vmcnt(16)" ::: "memory");  // current tile's 16 done
    } else {
      asm volatile("s_waitcnt vmcnt(0)" ::: "memory");
    }
    asm volatile("" ::: "memory");
    __builtin_amdgcn_s_barrier();        // all waves' stage loads landed
    asm volatile("" ::: "memory");

    // ---- MLP for atom = tile*256 + tid, x row from LDS (swizzled b128) ----
    const float* xrow = &xs[buf][tid * 64];
    v2f h[16];
#pragma unroll
    for (int j = 0; j < 16; ++j) h[j] = ((const v2f*)b1)[j];
#pragma unroll
    for (int q = 0; q < 16; ++q) {
      float4 xq = *(const float4*)(xrow + ((q ^ key) << 2));
      float xsc[4] = {xq.x, xq.y, xq.z, xq.w};
#pragma unroll
      for (int dd = 0; dd < 4; ++dd) {
        v2f xd2 = {xsc[dd], xsc[dd]};
        const v2f* wrow = ((const v2f*)W1) + (q * 4 + dd) * 16;
#pragma unroll
        for (int jj = 0; jj < 16; ++jj)
          h[jj] = __builtin_elementwise_fma(xd2, wrow[jj], h[jj]);
      }
    }
    float l0 = b2[0], l1 = b2[1], l2 = b2[2];
#pragma unroll
    for (int jj = 0; jj < 16; ++jj) {
#pragma unroll
      for (int cc = 0; cc < 2; ++cc) {
        float hj = h[jj][cc];
        float s = hj * __builtin_amdgcn_rcpf(1.0f + __expf(-hj));  // SiLU
        int k = 2 * jj + cc;
        l0 = fmaf(s, W2[k * 3 + 0], l0);
        l1 = fmaf(s, W2[k * 3 + 1], l1);
        l2 = fmaf(s, W2[k * 3 + 2], l2);
      }
    }
    const int aabs = tile * K1_TILE + tid;
    if (aabs < n_atoms) logits4[aabs] = make_float4(l0, l1, l2, 0.f);

    asm volatile("" ::: "memory");
    __builtin_amdgcn_s_barrier();        // everyone done reading buf before overwrite
    asm volatile("" ::: "memory");
    buf ^= 1;
  }
}

// ---------------- K3: segment softmax + pooling ----------------
// One wave per graph, 4 waves/block (no block barriers; waves decoupled),
// tiny LDS e-cache -> 32 waves/CU. Pool: 1 coalesced x-load + 1 broadcast
// ds_read_b128 + 3 fma per atom. Accumulate unnormalized, scale by 1/d at end.
__global__ __launch_bounds__(GPB * 64, 8) void gar_pool(
    const float* __restrict__ atom_feas,
    const int*   __restrict__ starts,
    const float4* __restrict__ logits4,
    float* __restrict__ out, int n_graphs)
{
  __shared__ __align__(16) float4 e4[GPB][LCAP];  // 16 KB/block
  const int w = threadIdx.x >> 6, t = threadIdx.x & 63;
  const int g = blockIdx.x * GPB + w;
  if (g >= n_graphs) return;
  const int s0 = starts[g];
  const int n  = starts[g + 1] - s0;
  float* __restrict__ outg = out + (size_t)g * (NFEA * NHEAD);
  if (n <= 0) {
    outg[t * 3 + 0] = 0.f; outg[t * 3 + 1] = 0.f; outg[t * 3 + 2] = 0.f;
    return;
  }

  // pass 1a: logits -> regs (first 4 chunks), running max
  float lr[4][3];
  float m0 = -INFINITY, m1 = -INFINITY, m2 = -INFINITY;
#pragma unroll
  for (int c = 0; c < 4; ++c) {
    if (c * 64 < n) {                        // wave-uniform skip
      int i = c * 64 + t;
      bool act = i < n;
      float4 lv = logits4[s0 + (act ? i : 0)];
      lr[c][0] = act ? lv.x : -INFINITY;
      lr[c][1] = act ? lv.y : -INFINITY;
      lr[c][2] = act ? lv.z : -INFINITY;
      m0 = fmaxf(m0, lr[c][0]); m1 = fmaxf(m1, lr[c][1]); m2 = fmaxf(m2, lr[c][2]);
    } else {
      lr[c][0] = -INFINITY; lr[c][1] = -INFINITY; lr[c][2] = -INFINITY;
    }
  }
  for (int i = 4 * 64 + t; i < n; i += 64) {  // overflow (cold)
    float4 lv = logits4[s0 + i];
    m0 = fmaxf(m0, lv.x); m1 = fmaxf(m1, lv.y); m2 = fmaxf(m2, lv.z);
  }
#pragma unroll
  for (int off = 32; off > 0; off >>= 1) {
    m0 = fmaxf(m0, __shfl_xor(m0, off));
    m1 = fmaxf(m1, __shfl_xor(m1, off));
    m2 = fmaxf(m2, __shfl_xor(m2, off));
  }

  // pass 1b: e = exp(l - m) -> LDS cache, denominator partials
  float d0 = 0.f, d1 = 0.f, d2 = 0.f;
#pragma unroll
  for (int c = 0; c < 4; ++c) {
    if (c * 64 < n) {
      float e0 = __expf(lr[c][0] - m0);  // inactive lanes: -inf -> 0
      float e1 = __expf(lr[c][1] - m1);
      float e2 = __expf(lr[c][2] - m2);
      d0 += e0; d1 += e1; d2 += e2;
      e4[w][c * 64 + t] = make_float4(e0, e1, e2, 0.f);
    }
  }
  for (int i = 4 * 64 + t; i < n; i += 64) {  // overflow (cold): d only
    float4 lv = logits4[s0 + i];
    d0 += __expf(lv.x - m0); d1 += __expf(lv.y - m1); d2 += __expf(lv.z - m2);
  }
#pragma unroll
  for (int off = 32; off > 0; off >>= 1) {
    d0 += __shfl_xor(d0, off);
    d1 += __shfl_xor(d1, off);
    d2 += __shfl_xor(d2, off);
  }
  wave_sync_lds();  // own-wave ds_writes retired before broadcast reads

  // pass 2: pooling. lane = feature t.
  float a0 = 0.f, a1 = 0.f, a2 = 0.f;
  const float* __restrict__ xcol = atom_feas + (size_t)s0 * NFEA + t;
  const int nmain = n < LCAP ? n : LCAP;
#pragma unroll 4
  for (int a = 0; a < nmain; ++a) {
    float  xv = xcol[(size_t)a * NFEA];
    float4 ev = e4[w][a];                    // same-address broadcast
    a0 = fmaf(ev.x, xv, a0);
    a1 = fmaf(ev.y, xv, a1);
    a2 = fmaf(ev.z, xv, a2);
  }
  for (int a = LCAP; a < n; ++a) {           // overflow (cold): recompute e
    float4 lv = logits4[s0 + a];
    float  xv = xcol[(size_t)a * NFEA];
    a0 = fmaf(__expf(lv.x - m0), xv, a0);
    a1 = fmaf(__expf(lv.y - m1), xv, a1);
    a2 = fmaf(__expf(lv.z - m2), xv, a2);
  }

  const float i0 = 1.f / d0, i1 = 1.f / d1, i2 = 1.f / d2;  // d >= 1 always
  outg[t * 3 + 0] = a0 * i0;
  outg[t * 3 + 1] = a1 * i1;
  outg[t * 3 + 2] = a2 * i2;
}

extern "C" void kernel_launch(void* const* d_in, const int* in_sizes, int n_in,
                              void* d_out, int out_size, void* d_ws, size_t ws_size,
                              hipStream_t stream)
{
  const float* atom_feas = (const float*)d_in[0];
  const int*   owner     = (const int*)d_in[1];
  const float* W1        = (const float*)d_in[2];
  const float* b1        = (const float*)d_in[3];
  const float* W2        = (const float*)d_in[4];
  const float* b2        = (const float*)d_in[5];
  float* out = (float*)d_out;

  const int n_atoms  = in_sizes[1];
  const int n_graphs = out_size / (NFEA * NHEAD);

  // ws layout: starts[n_graphs+1] | pad to 256B | logits4[n_atoms] (16B each)
  int* starts = (int*)d_ws;
  const size_t log_off = (((size_t)(n_graphs + 1) * sizeof(int)) + 255) & ~(size_t)255;
  float4* logits4 = (float4*)((char*)d_ws + log_off);

  const int n_tiles = (n_atoms + K1_TILE - 1) / K1_TILE;
  const int k1_grid = n_tiles < 256 ? n_tiles : 256;

  hipLaunchKernelGGL(gar_starts, dim3((n_atoms + 255) / 256), dim3(256), 0, stream,
                     owner, starts, n_atoms, n_graphs);
  hipLaunchKernelGGL(gar_mlp, dim3(k1_grid), dim3(K1_T), 0, stream,
                     atom_feas, W1, b1, W2, b2, logits4, n_atoms, n_tiles);
  hipLaunchKernelGGL(gar_pool, dim3((n_graphs + GPB - 1) / GPB), dim3(GPB * 64), 0, stream,
                     atom_feas, starts, logits4, out, n_graphs);
}

// Round 5
// 418.269 us; speedup vs baseline: 1.1981x; 1.1981x over previous
//
#include <hip/hip_runtime.h>
#include <math.h>
#include <stdint.h>

#define NFEA   64
#define NHEAD  3
#define GPB    4     // waves (graphs) per pool block
#define LCAP   256   // atoms per graph cached as float4 e-values (4 KB/wave)

typedef float v2f __attribute__((ext_vector_type(2)));

__device__ __forceinline__ void wave_sync_lds() {
  asm volatile("s_waitcnt lgkmcnt(0)" ::: "memory");
}

// ---------------- segment starts from sorted owner ----------------
__global__ void gar_starts(const int* __restrict__ owner, int* __restrict__ starts,
                           int n_atoms, int n_graphs)
{
  int a = blockIdx.x * blockDim.x + threadIdx.x;
  if (a >= n_atoms) return;
  int cur  = owner[a];
  int prev = (a == 0) ? -1 : owner[a - 1];
  for (int g = prev + 1; g <= cur; ++g) starts[g] = a;
  if (a == n_atoms - 1)
    for (int g = cur + 1; g <= n_graphs; ++g) starts[g] = n_atoms;
}

// ---------------- K1: atom-parallel MLP -> logits4[N] ----------------
// No LDS, no barriers. One thread = one atom. Full x-row prefetched into
// 16 float4 VGPRs with all loads in flight together (MSHR-merges the 8
// same-line requests); launch_bounds(256,4) keeps VGPR <= 128 so the row
// buffer lives in registers (R1's 32-VGPR squeeze was what exploded FETCH).
__global__ __launch_bounds__(256, 4) void gar_mlp(
    const float* __restrict__ atom_feas,
    const float* __restrict__ W1, const float* __restrict__ b1,
    const float* __restrict__ W2, const float* __restrict__ b2,
    float4* __restrict__ logits4, int n_atoms)
{
  const int a = blockIdx.x * 256 + threadIdx.x;
  if (a >= n_atoms) return;
  const float4* __restrict__ xrow = (const float4*)(atom_feas + (size_t)a * NFEA);

  float4 xr[16];
#pragma unroll
  for (int q = 0; q < 16; ++q) xr[q] = xrow[q];   // 16 loads back-to-back

  v2f h[16];
#pragma unroll
  for (int j = 0; j < 16; ++j) h[j] = ((const v2f*)b1)[j];

#pragma unroll
  for (int q = 0; q < 16; ++q) {
    float xs[4] = {xr[q].x, xr[q].y, xr[q].z, xr[q].w};
#pragma unroll
    for (int dd = 0; dd < 4; ++dd) {
      v2f xd2 = {xs[dd], xs[dd]};
      const v2f* wrow = ((const v2f*)W1) + (q * 4 + dd) * 16;   // wave-uniform: s_load
#pragma unroll
      for (int jj = 0; jj < 16; ++jj)
        h[jj] = __builtin_elementwise_fma(xd2, wrow[jj], h[jj]);
    }
  }

  float l0 = b2[0], l1 = b2[1], l2 = b2[2];
#pragma unroll
  for (int jj = 0; jj < 16; ++jj) {
#pragma unroll
    for (int cc = 0; cc < 2; ++cc) {
      float hj = h[jj][cc];
      float s = hj * __builtin_amdgcn_rcpf(1.0f + __expf(-hj));  // SiLU
      int k = 2 * jj + cc;
      l0 = fmaf(s, W2[k * 3 + 0], l0);
      l1 = fmaf(s, W2[k * 3 + 1], l1);
      l2 = fmaf(s, W2[k * 3 + 2], l2);
    }
  }
  logits4[a] = make_float4(l0, l1, l2, 0.f);
}

// ---------------- K3: segment softmax + pooling ----------------
// One wave per graph, 4 waves/block (no block barriers; waves decoupled),
// tiny LDS e-cache -> 32 waves/CU. Pool: 1 coalesced x-load + 1 broadcast
// ds_read_b128 + 3 fma per atom. Accumulate unnormalized, scale by 1/d at end.
__global__ __launch_bounds__(GPB * 64, 8) void gar_pool(
    const float* __restrict__ atom_feas,
    const int*   __restrict__ starts,
    const float4* __restrict__ logits4,
    float* __restrict__ out, int n_graphs)
{
  __shared__ __align__(16) float4 e4[GPB][LCAP];  // 16 KB/block
  const int w = threadIdx.x >> 6, t = threadIdx.x & 63;
  const int g = blockIdx.x * GPB + w;
  if (g >= n_graphs) return;
  const int s0 = starts[g];
  const int n  = starts[g + 1] - s0;
  float* __restrict__ outg = out + (size_t)g * (NFEA * NHEAD);
  if (n <= 0) {
    outg[t * 3 + 0] = 0.f; outg[t * 3 + 1] = 0.f; outg[t * 3 + 2] = 0.f;
    return;
  }

  // pass 1a: logits -> regs (first 4 chunks), running max
  float lr[4][3];
  float m0 = -INFINITY, m1 = -INFINITY, m2 = -INFINITY;
#pragma unroll
  for (int c = 0; c < 4; ++c) {
    if (c * 64 < n) {                        // wave-uniform skip
      int i = c * 64 + t;
      bool act = i < n;
      float4 lv = logits4[s0 + (act ? i : 0)];
      lr[c][0] = act ? lv.x : -INFINITY;
      lr[c][1] = act ? lv.y : -INFINITY;
      lr[c][2] = act ? lv.z : -INFINITY;
      m0 = fmaxf(m0, lr[c][0]); m1 = fmaxf(m1, lr[c][1]); m2 = fmaxf(m2, lr[c][2]);
    } else {
      lr[c][0] = -INFINITY; lr[c][1] = -INFINITY; lr[c][2] = -INFINITY;
    }
  }
  for (int i = 4 * 64 + t; i < n; i += 64) {  // overflow (cold)
    float4 lv = logits4[s0 + i];
    m0 = fmaxf(m0, lv.x); m1 = fmaxf(m1, lv.y); m2 = fmaxf(m2, lv.z);
  }
#pragma unroll
  for (int off = 32; off > 0; off >>= 1) {
    m0 = fmaxf(m0, __shfl_xor(m0, off));
    m1 = fmaxf(m1, __shfl_xor(m1, off));
    m2 = fmaxf(m2, __shfl_xor(m2, off));
  }

  // pass 1b: e = exp(l - m) -> LDS cache, denominator partials
  float d0 = 0.f, d1 = 0.f, d2 = 0.f;
#pragma unroll
  for (int c = 0; c < 4; ++c) {
    if (c * 64 < n) {
      float e0 = __expf(lr[c][0] - m0);  // inactive lanes: -inf -> 0
      float e1 = __expf(lr[c][1] - m1);
      float e2 = __expf(lr[c][2] - m2);
      d0 += e0; d1 += e1; d2 += e2;
      e4[w][c * 64 + t] = make_float4(e0, e1, e2, 0.f);
    }
  }
  for (int i = 4 * 64 + t; i < n; i += 64) {  // overflow (cold): d only
    float4 lv = logits4[s0 + i];
    d0 += __expf(lv.x - m0); d1 += __expf(lv.y - m1); d2 += __expf(lv.z - m2);
  }
#pragma unroll
  for (int off = 32; off > 0; off >>= 1) {
    d0 += __shfl_xor(d0, off);
    d1 += __shfl_xor(d1, off);
    d2 += __shfl_xor(d2, off);
  }
  wave_sync_lds();  // own-wave ds_writes retired before broadcast reads

  // pass 2: pooling. lane = feature t.
  float a0 = 0.f, a1 = 0.f, a2 = 0.f;
  const float* __restrict__ xcol = atom_feas + (size_t)s0 * NFEA + t;
  const int nmain = n < LCAP ? n : LCAP;
#pragma unroll 4
  for (int a = 0; a < nmain; ++a) {
    float  xv = xcol[(size_t)a * NFEA];
    float4 ev = e4[w][a];                    // same-address broadcast
    a0 = fmaf(ev.x, xv, a0);
    a1 = fmaf(ev.y, xv, a1);
    a2 = fmaf(ev.z, xv, a2);
  }
  for (int a = LCAP; a < n; ++a) {           // overflow (cold): recompute e
    float4 lv = logits4[s0 + a];
    float  xv = xcol[(size_t)a * NFEA];
    a0 = fmaf(__expf(lv.x - m0), xv, a0);
    a1 = fmaf(__expf(lv.y - m1), xv, a1);
    a2 = fmaf(__expf(lv.z - m2), xv, a2);
  }

  const float i0 = 1.f / d0, i1 = 1.f / d1, i2 = 1.f / d2;  // d >= 1 always
  outg[t * 3 + 0] = a0 * i0;
  outg[t * 3 + 1] = a1 * i1;
  outg[t * 3 + 2] = a2 * i2;
}

extern "C" void kernel_launch(void* const* d_in, const int* in_sizes, int n_in,
                              void* d_out, int out_size, void* d_ws, size_t ws_size,
                              hipStream_t stream)
{
  const float* atom_feas = (const float*)d_in[0];
  const int*   owner     = (const int*)d_in[1];
  const float* W1        = (const float*)d_in[2];
  const float* b1        = (const float*)d_in[3];
  const float* W2        = (const float*)d_in[4];
  const float* b2        = (const float*)d_in[5];
  float* out = (float*)d_out;

  const int n_atoms  = in_sizes[1];
  const int n_graphs = out_size / (NFEA * NHEAD);

  // ws layout: starts[n_graphs+1] | pad to 256B | logits4[n_atoms] (16B each)
  int* starts = (int*)d_ws;
  const size_t log_off = (((size_t)(n_graphs + 1) * sizeof(int)) + 255) & ~(size_t)255;
  float4* logits4 = (float4*)((char*)d_ws + log_off);

  hipLaunchKernelGGL(gar_starts, dim3((n_atoms + 255) / 256), dim3(256), 0, stream,
                     owner, starts, n_atoms, n_graphs);
  hipLaunchKernelGGL(gar_mlp, dim3((n_atoms + 255) / 256), dim3(256), 0, stream,
                     atom_feas, W1, b1, W2, b2, logits4, n_atoms);
  hipLaunchKernelGGL(gar_pool, dim3((n_graphs + GPB - 1) / GPB), dim3(GPB * 64), 0, stream,
                     atom_feas, starts, logits4, out, n_graphs);
}